// Round 17
// baseline (406.009 us; speedup 1.0000x reference)
//
#include <hip/hip_runtime.h>
#include <hip/hip_bf16.h>

// Problem constants
#define NN    8
#define CC    32
#define HH    48
#define WW    48
#define OCC   32
#define HID   256
#define FEAT  288          // C*K*K
#define RTOT  9216         // (H*S)*(W*S)
#define COLS  9216         // FEAT*OC
#define XUP   96
#define YUP   96
#define OUTSZ (NN*OCC*XUP*YUP)   // 2,359,296 floats

using bf16x8 = __attribute__((ext_vector_type(8))) __bf16;
using bf16x4 = __attribute__((ext_vector_type(4))) __bf16;
using f32x4  = __attribute__((ext_vector_type(4))) float;

#define GLOAD_LDS16(gp, lp)                                                        \
  __builtin_amdgcn_global_load_lds((const __attribute__((address_space(1))) void*)(gp), \
                                   (__attribute__((address_space(3))) void*)(lp), 16, 0, 0)

// ---------------------------------------------------------------------------
// Kernel 1: hmid = relu(v @ w1 + b1), bf16, MFMA A-fragment order (verified):
//   frag = (r/16)*8 + k/32 ; lane = ((k/8)%4)*16 + r%16 ; elem = k%8
// ---------------------------------------------------------------------------
__global__ void prep_hmid(const float* __restrict__ v, const float* __restrict__ w1,
                          const float* __restrict__ b1, __hip_bfloat16* __restrict__ hmidp) {
  int r = blockIdx.x;      // 0..9215
  int t = threadIdx.x;     // 0..255 = hidden index k
  float v0 = v[r*3+0], v1 = v[r*3+1], v2 = v[r*3+2];
  float val = v0*w1[t] + v1*w1[HID+t] + v2*w1[2*HID+t] + b1[t];
  val = fmaxf(val, 0.0f);
  int dst = ((r>>4)*8 + (t>>5))*512 + ((t>>3)&3)*128 + (r&15)*8 + (t&7);
  hmidp[dst] = __float2bfloat16(val);
}

// ---------------------------------------------------------------------------
// Kernel 2: w2 -> bf16, B-fragment order grouped into 8KB slices (verified):
//   colchunk = col/128 (72), kb = k/32 (8), cg = (col%128)/16 (8),
//   lane = ((k/8)%4)*16 + col%16, elem = k%8
// ---------------------------------------------------------------------------
__global__ void prep_w2(const float* __restrict__ w2, __hip_bfloat16* __restrict__ w2p) {
  int idx = blockIdx.x*256 + threadIdx.x;   // 0 .. 256*9216-1
  int k   = idx / COLS;
  int col = idx % COLS;
  float val = w2[idx];                      // w2[k][col], row-major
  int colchunk = col >> 7;
  int cg   = (col >> 4) & 7;
  int lane = (((k>>3)&3)<<4) | (col & 15);
  int kb   = k >> 5;
  int i    = k & 7;
  int dst  = (((colchunk*8 + kb)*8 + cg)*64 + lane)*8 + i;
  w2p[dst] = __float2bfloat16(val);
}

// ---------------------------------------------------------------------------
// Kernel 3: fused GEMM + apply — R12 core (passed; A-tile in LDS, VGPR 92),
// R17 CHANGE (one mechanism): B prefetch loads are VOLATILE.
//   R11/R12 post-mortem: const __restrict loads are invariant -> they legally
//   sank past every asm "memory" fence to their use point, so the "double
//   buffer" never existed and each half-chunk ate naked L2 latency. volatile
//   pins the ISSUE point (before wc-write + 2 barriers + apply = the cover),
//   while s_waitcnt still lands at first use (next chunk's MFMA).
// LDS (dynamic): Atile 16384 + pat 27648 + wc 16384 + biasL = 65,024 (G=2).
// ---------------------------------------------------------------------------
#define BARRIER_LGKM() do {                              \
    asm volatile("s_waitcnt lgkmcnt(0)" ::: "memory");   \
    __builtin_amdgcn_sched_barrier(0);                   \
    __builtin_amdgcn_s_barrier();                        \
  } while (0)

#define ISSUE_HALF(SET, CH, H) do {                                              \
    const char* _b = w2base + ((size_t)((CH)*8 + (H)*4))*8192 + wv*2048          \
                     + (size_t)lane*16;                                          \
    _Pragma("unroll")                                                            \
    for (int _i = 0; _i < 4; ++_i) {                                             \
      SET[0][_i] = *(const volatile bf16x8*)(_b + _i*8192);                      \
      SET[1][_i] = *(const volatile bf16x8*)(_b + _i*8192 + 1024);               \
    }                                                                            \
  } while (0)

__launch_bounds__(256, 2)
__global__ void fused_main(const float* __restrict__ F_LR,
                           const __hip_bfloat16* __restrict__ hmidp,
                           const __hip_bfloat16* __restrict__ w2p,
                           const float* __restrict__ b2,
                           float* __restrict__ outp,
                           int G, int nch) {
  extern __shared__ __align__(16) char smem[];
  char*   AtileB = smem;                         // 16384B: [mg*8+kb][lane][8] bf16
  __bf16* patB   = (__bf16*)(smem + 16384);      // 27648B: pat[c][ki][wi(18)][n(8)]
  float*  wc     = (float*)(smem + 44032);       // 16384B: [fl][oc][r^swz]
  __bf16* biasL  = (__bf16*)(smem + 60416);      // nch*128 bf16

  const int tid  = threadIdx.x;
  const int lane = tid & 63;
  const int wv   = tid >> 6;
  const int blk  = blockIdx.x;
  int rowtile, g;
  if (G == 2) {            // XCD-chunked decode (grid = 576, 72 blocks per XCD)
    int xcd = blk & 7;
    int j   = blk >> 3;    // 0..71
    g       = xcd & 1;
    rowtile = (xcd >> 1)*72 + j;
  } else {
    rowtile = blk;
    g       = 0;
  }
  const int X  = rowtile / 3;
  const int Yh = rowtile - X*3;
  const int h  = X >> 1;
  const int w0 = Yh * 16;
  const int l15 = lane & 15;
  const int qt  = lane >> 4;
  const int oc  = lane & 31;
  const int nh  = lane >> 5;

  const char* w2base = (const char*)w2p + (size_t)g*nch*65536;

  // ---- A tile -> LDS (16KB linear, R2/R12-proven global_load_lds) ----
  {
    const char* hsrc = (const char*)hmidp + (size_t)rowtile*16384;
    #pragma unroll
    for (int j = 0; j < 4; ++j)
      GLOAD_LDS16(hsrc + j*4096 + wv*1024 + lane*16, AtileB + j*4096 + wv*1024);
  }

  // ---- bias table -> LDS (bf16, one-time) ----
  for (int i = tid; i < nch*128; i += 256)
    biasL[i] = (__bf16)b2[g*nch*128 + i];

  // ---- stage patches: pat[c][ki][wi][n]; thread = (n,c) ----
  {
    const int n = tid >> 5, c = tid & 31;
    const float* fsrc = F_LR + ((size_t)(n*CC + c)*HH)*WW;
    #pragma unroll
    for (int ki = 0; ki < 3; ++ki) {
      int hh = h - 1 + ki;
      bool hok = (unsigned)hh < (unsigned)HH;
      #pragma unroll
      for (int wi = 0; wi < 18; ++wi) {
        int ww = w0 - 1 + wi;
        float val = (hok && (unsigned)ww < (unsigned)WW) ? fsrc[hh*WW + ww] : 0.f;
        patB[((c*3 + ki)*18 + wi)*8 + n] = (__bf16)val;
      }
    }
  }
  asm volatile("s_waitcnt vmcnt(0) lgkmcnt(0)" ::: "memory");
  __builtin_amdgcn_sched_barrier(0);
  __builtin_amdgcn_s_barrier();                  // Atile/pat/bias all visible

  float oacc[8][4];
  #pragma unroll
  for (int i = 0; i < 8; ++i)
    { oacc[i][0]=0.f; oacc[i][1]=0.f; oacc[i][2]=0.f; oacc[i][3]=0.f; }

  // ---- B double buffer: two half-chunk register sets (volatile-pinned) ----
  bf16x8 bA[2][4], bB[2][4];
  ISSUE_HALF(bA, 0, 0);
  ISSUE_HALF(bB, 0, 1);

  for (int ch = 0; ch < nch; ++ch) {
    f32x4 acc00 = {0,0,0,0}, acc01 = {0,0,0,0}, acc10 = {0,0,0,0}, acc11 = {0,0,0,0};

    // ---- consume half A (slices 0..3; A frags from LDS), refill for ch+1 ----
    #pragma unroll
    for (int s = 0; s < 4; ++s) {
      bf16x8 a0 = *(const bf16x8*)(AtileB + s*1024 + lane*16);
      bf16x8 a1 = *(const bf16x8*)(AtileB + 8192 + s*1024 + lane*16);
      acc00 = __builtin_amdgcn_mfma_f32_16x16x32_bf16(a0, bA[0][s], acc00, 0,0,0);
      acc01 = __builtin_amdgcn_mfma_f32_16x16x32_bf16(a0, bA[1][s], acc01, 0,0,0);
      acc10 = __builtin_amdgcn_mfma_f32_16x16x32_bf16(a1, bA[0][s], acc10, 0,0,0);
      acc11 = __builtin_amdgcn_mfma_f32_16x16x32_bf16(a1, bA[1][s], acc11, 0,0,0);
    }
    if (ch + 1 < nch) { ISSUE_HALF(bA, ch+1, 0); }

    // ---- consume half B (slices 4..7), refill for ch+1 ----
    #pragma unroll
    for (int s = 0; s < 4; ++s) {
      bf16x8 a0 = *(const bf16x8*)(AtileB + (4+s)*1024 + lane*16);
      bf16x8 a1 = *(const bf16x8*)(AtileB + 8192 + (4+s)*1024 + lane*16);
      acc00 = __builtin_amdgcn_mfma_f32_16x16x32_bf16(a0, bB[0][s], acc00, 0,0,0);
      acc01 = __builtin_amdgcn_mfma_f32_16x16x32_bf16(a0, bB[1][s], acc01, 0,0,0);
      acc10 = __builtin_amdgcn_mfma_f32_16x16x32_bf16(a1, bB[0][s], acc10, 0,0,0);
      acc11 = __builtin_amdgcn_mfma_f32_16x16x32_bf16(a1, bB[1][s], acc11, 0,0,0);
    }
    if (ch + 1 < nch) { ISSUE_HALF(bB, ch+1, 1); }

    // ---- wc write: wc[fl(=wv)][oc][r^swz] = acc + bias ----
    {
      float bias0 = (float)biasL[ch*128 + wv*32 + l15];
      float bias1 = (float)biasL[ch*128 + wv*32 + 16 + l15];
      #pragma unroll
      for (int mg = 0; mg < 2; ++mg) {
        #pragma unroll
        for (int ng = 0; ng < 2; ++ng) {
          f32x4 A = (mg==0) ? (ng==0?acc00:acc01) : (ng==0?acc10:acc11);
          float bb = ng ? bias1 : bias0;
          A[0]+=bb; A[1]+=bb; A[2]+=bb; A[3]+=bb;
          int ocx  = ng*16 + l15;
          int ridx = (mg*16 + qt*4) ^ ((ocx&7)<<2);
          *(f32x4*)&wc[wv*1024 + ocx*32 + ridx] = A;
        }
      }
    }
    BARRIER_LGKM();                        // wc visible (vmem stays in flight)

    // ---- apply ----
    const int swz = (oc & 7) << 2;
    #pragma unroll
    for (int fl = 0; fl < 4; ++fl) {
      const int f   = (g*nch + ch)*4 + fl;
      const int c   = f / 9;
      const int rem = f - c*9;
      const int ki  = rem / 3;
      const int kj  = rem - ki*3;
      const f32x4 wlo = *(const f32x4*)&wc[fl*1024 + oc*32 + ((wv*8    ) ^ swz)];
      const f32x4 whi = *(const f32x4*)&wc[fl*1024 + oc*32 + ((wv*8 + 4) ^ swz)];
      const __bf16* pbase = patB + (c*3 + ki)*144 + nh*4;
      #pragma unroll
      for (int rrh = 0; rrh < 4; ++rrh) {
        bf16x4 pq = *(const bf16x4*)(pbase + (wv*4 + rrh + kj)*8);
        float w0v = (rrh < 2) ? ((rrh == 0) ? wlo[0] : wlo[2]) : ((rrh == 2) ? whi[0] : whi[2]);
        float w1v = (rrh < 2) ? ((rrh == 0) ? wlo[1] : wlo[3]) : ((rrh == 2) ? whi[1] : whi[3]);
        #pragma unroll
        for (int q = 0; q < 4; ++q) {
          float pv = (float)pq[q];
          oacc[rrh*2][q]   += w0v * pv;
          oacc[rrh*2+1][q] += w1v * pv;
        }
      }
    }
    BARRIER_LGKM();                        // apply done; wc reusable
  }

  // ---- epilogue: out[n, oc, X, Yh*32 + wv*8 .. +7] ----
  float* OP = outp + (size_t)g*OUTSZ;
  #pragma unroll
  for (int q = 0; q < 4; ++q) {
    int n = nh*4 + q;
    f32x4 v0, v1;
    v0[0]=oacc[0][q]; v0[1]=oacc[1][q]; v0[2]=oacc[2][q]; v0[3]=oacc[3][q];
    v1[0]=oacc[4][q]; v1[1]=oacc[5][q]; v1[2]=oacc[6][q]; v1[3]=oacc[7][q];
    float* dst = OP + (((size_t)(n*OCC + oc)*XUP + X)*YUP + Yh*32 + wv*8);
    *(f32x4*)dst     = v0;
    *(f32x4*)(dst+4) = v1;
  }
}

// ---------------------------------------------------------------------------
// Kernel 4 (G=2 only): out = P0 + P1 (deterministic)
// ---------------------------------------------------------------------------
__global__ void reduce2(const float* __restrict__ P, float* __restrict__ out) {
  int i = blockIdx.x*256 + threadIdx.x;
  if (i < OUTSZ/4) {
    f32x4 a = ((const f32x4*)P)[i];
    f32x4 b = ((const f32x4*)(P + OUTSZ))[i];
    ((f32x4*)out)[i] = a + b;
  }
}

// ---------------------------------------------------------------------------
extern "C" void kernel_launch(void* const* d_in, const int* in_sizes, int n_in,
                              void* d_out, int out_size, void* d_ws, size_t ws_size,
                              hipStream_t stream) {
  const float* F_LR = (const float*)d_in[0];
  const float* v    = (const float*)d_in[1];
  const float* w1   = (const float*)d_in[2];
  const float* b1   = (const float*)d_in[3];
  const float* w2   = (const float*)d_in[4];
  const float* b2   = (const float*)d_in[5];
  float* out = (float*)d_out;

  const size_t prepBytes = (size_t)RTOT*HID*2;          // 4,718,592 each
  const size_t need2 = 2*prepBytes + 2ull*OUTSZ*4;      // 28,311,552
  const int G   = (ws_size >= need2) ? 2 : 1;
  const int nch = 72 / G;

  __hip_bfloat16* hmidp = (__hip_bfloat16*)d_ws;
  __hip_bfloat16* w2p   = (__hip_bfloat16*)((char*)d_ws + prepBytes);
  float* P = (float*)((char*)d_ws + 2*prepBytes);
  float* target = (G == 2) ? P : out;

  const size_t shmem = 16384 + 27648 + 16384 + (size_t)nch*128*2;   // 65,024 (G=2)

  hipLaunchKernelGGL(prep_hmid, dim3(RTOT), dim3(HID), 0, stream, v, w1, b1, hmidp);
  hipLaunchKernelGGL(prep_w2,   dim3((HID*COLS)/256), dim3(256), 0, stream, w2, w2p);
  hipLaunchKernelGGL(fused_main, dim3(288*G), dim3(256), shmem, stream,
                     F_LR, hmidp, w2p, b2, target, G, nch);
  if (G == 2)
    hipLaunchKernelGGL(reduce2, dim3(OUTSZ/4/256), dim3(256), 0, stream, P, out);
}

// Round 18
// 183.055 us; speedup vs baseline: 2.2180x; 2.2180x over previous
//
#include <hip/hip_runtime.h>
#include <hip/hip_bf16.h>

// Problem constants
#define NN    8
#define CC    32
#define HH    48
#define WW    48
#define OCC   32
#define HID   256
#define FEAT  288          // C*K*K
#define RTOT  9216         // (H*S)*(W*S)
#define COLS  9216         // FEAT*OC
#define XUP   96
#define YUP   96
#define OUTSZ (NN*OCC*XUP*YUP)   // 2,359,296 floats

using bf16x8 = __attribute__((ext_vector_type(8))) __bf16;
using bf16x4 = __attribute__((ext_vector_type(4))) __bf16;
using f32x4  = __attribute__((ext_vector_type(4))) float;

#define GLOAD_LDS16(gp, lp)                                                        \
  __builtin_amdgcn_global_load_lds((const __attribute__((address_space(1))) void*)(gp), \
                                   (__attribute__((address_space(3))) void*)(lp), 16, 0, 0)

// ---------------------------------------------------------------------------
// Kernel 1: hmid = relu(v @ w1 + b1), bf16, MFMA A-fragment order (verified):
//   frag = (r/16)*8 + k/32 ; lane = ((k/8)%4)*16 + r%16 ; elem = k%8
// ---------------------------------------------------------------------------
__global__ void prep_hmid(const float* __restrict__ v, const float* __restrict__ w1,
                          const float* __restrict__ b1, __hip_bfloat16* __restrict__ hmidp) {
  int r = blockIdx.x;      // 0..9215
  int t = threadIdx.x;     // 0..255 = hidden index k
  float v0 = v[r*3+0], v1 = v[r*3+1], v2 = v[r*3+2];
  float val = v0*w1[t] + v1*w1[HID+t] + v2*w1[2*HID+t] + b1[t];
  val = fmaxf(val, 0.0f);
  int dst = ((r>>4)*8 + (t>>5))*512 + ((t>>3)&3)*128 + (r&15)*8 + (t&7);
  hmidp[dst] = __float2bfloat16(val);
}

// ---------------------------------------------------------------------------
// Kernel 2: w2 -> bf16, B-fragment order grouped into 8KB slices (verified):
//   colchunk = col/128 (72), kb = k/32 (8), cg = (col%128)/16 (8),
//   lane = ((k/8)%4)*16 + col%16, elem = k%8
// ---------------------------------------------------------------------------
__global__ void prep_w2(const float* __restrict__ w2, __hip_bfloat16* __restrict__ w2p) {
  int idx = blockIdx.x*256 + threadIdx.x;   // 0 .. 256*9216-1
  int k   = idx / COLS;
  int col = idx % COLS;
  float val = w2[idx];                      // w2[k][col], row-major
  int colchunk = col >> 7;
  int cg   = (col >> 4) & 7;
  int lane = (((k>>3)&3)<<4) | (col & 15);
  int kb   = k >> 5;
  int i    = k & 7;
  int dst  = (((colchunk*8 + kb)*8 + cg)*64 + lane)*8 + i;
  w2p[dst] = __float2bfloat16(val);
}

// ---------------------------------------------------------------------------
// Kernel 3: fused GEMM + apply — R12 core (passed incl. post-timing),
// R18 CHANGE (one mechanism): B prefetch via INLINE-ASM global_load_dwordx4
// into a ping-pong register set the compiler cannot sink/shrink (R11/R12/R17
// post-mortems: plain & volatile C++ loads always became load-at-use ->
// ~8K cy naked L2 latency per chunk). Consume after a conservative
// s_waitcnt vmcnt(0) + sched_barrier(0) (guide rule #18) at chunk top.
// Cover = MFMA + wc-write + 2 barriers + apply >> 500cy L2 latency.
// LDS (dynamic): Atile 16384 + pat 27648 + wc 16384 + biasL = 65,024 (G=2).
// ---------------------------------------------------------------------------
#define BARRIER_LGKM() do {                              \
    asm volatile("s_waitcnt lgkmcnt(0)" ::: "memory");   \
    __builtin_amdgcn_sched_barrier(0);                   \
    __builtin_amdgcn_s_barrier();                        \
  } while (0)

#define ASM_LOAD16(v4, addr)                                                     \
  asm volatile("global_load_dwordx4 %0, %1, off" : "=v"(v4) : "v"(addr))

// issue all 16 B-fragment loads for chunk CH into SET (asm-pinned)
#define ISSUE_CHUNK(SET, CH) do {                                                \
    const char* _base = w2base + (size_t)(CH)*65536 + wv*2048 + (size_t)lane*16; \
    _Pragma("unroll")                                                            \
    for (int _kb = 0; _kb < 8; ++_kb) {                                          \
      ASM_LOAD16(SET[0][_kb], _base + _kb*8192);                                 \
      ASM_LOAD16(SET[1][_kb], _base + _kb*8192 + 1024);                          \
    }                                                                            \
  } while (0)

__launch_bounds__(256, 2)
__global__ void fused_main(const float* __restrict__ F_LR,
                           const __hip_bfloat16* __restrict__ hmidp,
                           const __hip_bfloat16* __restrict__ w2p,
                           const float* __restrict__ b2,
                           float* __restrict__ outp,
                           int G, int nch) {
  extern __shared__ __align__(16) char smem[];
  char*   AtileB = smem;                         // 16384B: [mg*8+kb][lane][8] bf16
  __bf16* patB   = (__bf16*)(smem + 16384);      // 27648B: pat[c][ki][wi(18)][n(8)]
  float*  wc     = (float*)(smem + 44032);       // 16384B: [fl][oc][r^swz]
  __bf16* biasL  = (__bf16*)(smem + 60416);      // nch*128 bf16

  const int tid  = threadIdx.x;
  const int lane = tid & 63;
  const int wv   = tid >> 6;
  const int blk  = blockIdx.x;
  int rowtile, g;
  if (G == 2) {            // XCD-chunked decode (grid = 576, 72 blocks per XCD)
    int xcd = blk & 7;
    int j   = blk >> 3;    // 0..71
    g       = xcd & 1;
    rowtile = (xcd >> 1)*72 + j;
  } else {
    rowtile = blk;
    g       = 0;
  }
  const int X  = rowtile / 3;
  const int Yh = rowtile - X*3;
  const int h  = X >> 1;
  const int w0 = Yh * 16;
  const int l15 = lane & 15;
  const int qt  = lane >> 4;
  const int oc  = lane & 31;
  const int nh  = lane >> 5;

  const char* w2base = (const char*)w2p + (size_t)g*nch*65536;

  // ---- A tile -> LDS (16KB linear, R2/R12-proven global_load_lds) ----
  {
    const char* hsrc = (const char*)hmidp + (size_t)rowtile*16384;
    #pragma unroll
    for (int j = 0; j < 4; ++j)
      GLOAD_LDS16(hsrc + j*4096 + wv*1024 + lane*16, AtileB + j*4096 + wv*1024);
  }

  // ---- bias table -> LDS (bf16, one-time) ----
  for (int i = tid; i < nch*128; i += 256)
    biasL[i] = (__bf16)b2[g*nch*128 + i];

  // ---- stage patches: pat[c][ki][wi][n]; thread = (n,c) ----
  {
    const int n = tid >> 5, c = tid & 31;
    const float* fsrc = F_LR + ((size_t)(n*CC + c)*HH)*WW;
    #pragma unroll
    for (int ki = 0; ki < 3; ++ki) {
      int hh = h - 1 + ki;
      bool hok = (unsigned)hh < (unsigned)HH;
      #pragma unroll
      for (int wi = 0; wi < 18; ++wi) {
        int ww = w0 - 1 + wi;
        float val = (hok && (unsigned)ww < (unsigned)WW) ? fsrc[hh*WW + ww] : 0.f;
        patB[((c*3 + ki)*18 + wi)*8 + n] = (__bf16)val;
      }
    }
  }
  asm volatile("s_waitcnt vmcnt(0) lgkmcnt(0)" ::: "memory");
  __builtin_amdgcn_sched_barrier(0);
  __builtin_amdgcn_s_barrier();                  // Atile/pat/bias all visible

  float oacc[8][4];
  #pragma unroll
  for (int i = 0; i < 8; ++i)
    { oacc[i][0]=0.f; oacc[i][1]=0.f; oacc[i][2]=0.f; oacc[i][3]=0.f; }

  // ---- B ping-pong register sets (asm-held; compiler cannot sink) ----
  bf16x8 bufA[2][8], bufB[2][8];
  ISSUE_CHUNK(bufA, 0);

  // one chunk body: wait current set, prefetch next set, GEMM, wc, apply
#define CHUNK_BODY(CH, CUR, NXT) do {                                            \
    asm volatile("s_waitcnt vmcnt(0)" ::: "memory");                             \
    __builtin_amdgcn_sched_barrier(0);                                           \
    if ((CH) + 1 < nch) { ISSUE_CHUNK(NXT, (CH)+1); }                            \
    f32x4 acc00 = {0,0,0,0}, acc01 = {0,0,0,0}, acc10 = {0,0,0,0}, acc11 = {0,0,0,0}; \
    _Pragma("unroll")                                                            \
    for (int kb = 0; kb < 8; ++kb) {                                             \
      bf16x8 a0 = *(const bf16x8*)(AtileB + kb*1024 + lane*16);                  \
      bf16x8 a1 = *(const bf16x8*)(AtileB + 8192 + kb*1024 + lane*16);           \
      acc00 = __builtin_amdgcn_mfma_f32_16x16x32_bf16(a0, CUR[0][kb], acc00, 0,0,0); \
      acc01 = __builtin_amdgcn_mfma_f32_16x16x32_bf16(a0, CUR[1][kb], acc01, 0,0,0); \
      acc10 = __builtin_amdgcn_mfma_f32_16x16x32_bf16(a1, CUR[0][kb], acc10, 0,0,0); \
      acc11 = __builtin_amdgcn_mfma_f32_16x16x32_bf16(a1, CUR[1][kb], acc11, 0,0,0); \
    }                                                                            \
    {                                                                            \
      float bias0 = (float)biasL[(CH)*128 + wv*32 + l15];                        \
      float bias1 = (float)biasL[(CH)*128 + wv*32 + 16 + l15];                   \
      _Pragma("unroll")                                                          \
      for (int mg = 0; mg < 2; ++mg) {                                           \
        _Pragma("unroll")                                                        \
        for (int ng = 0; ng < 2; ++ng) {                                         \
          f32x4 A = (mg==0) ? (ng==0?acc00:acc01) : (ng==0?acc10:acc11);         \
          float bb = ng ? bias1 : bias0;                                         \
          A[0]+=bb; A[1]+=bb; A[2]+=bb; A[3]+=bb;                                \
          int ocx  = ng*16 + l15;                                                \
          int ridx = (mg*16 + qt*4) ^ ((ocx&7)<<2);                              \
          *(f32x4*)&wc[wv*1024 + ocx*32 + ridx] = A;                             \
        }                                                                        \
      }                                                                          \
    }                                                                            \
    BARRIER_LGKM();                                                              \
    {                                                                            \
      const int swz = (oc & 7) << 2;                                             \
      _Pragma("unroll")                                                          \
      for (int fl = 0; fl < 4; ++fl) {                                           \
        const int f   = (g*nch + (CH))*4 + fl;                                   \
        const int c   = f / 9;                                                   \
        const int rem = f - c*9;                                                 \
        const int ki  = rem / 3;                                                 \
        const int kj  = rem - ki*3;                                              \
        const f32x4 wlo = *(const f32x4*)&wc[fl*1024 + oc*32 + ((wv*8    ) ^ swz)]; \
        const f32x4 whi = *(const f32x4*)&wc[fl*1024 + oc*32 + ((wv*8 + 4) ^ swz)]; \
        const __bf16* pbase = patB + (c*3 + ki)*144 + nh*4;                      \
        _Pragma("unroll")                                                        \
        for (int rrh = 0; rrh < 4; ++rrh) {                                      \
          bf16x4 pq = *(const bf16x4*)(pbase + (wv*4 + rrh + kj)*8);             \
          float w0v = (rrh < 2) ? ((rrh == 0) ? wlo[0] : wlo[2]) : ((rrh == 2) ? whi[0] : whi[2]); \
          float w1v = (rrh < 2) ? ((rrh == 0) ? wlo[1] : wlo[3]) : ((rrh == 2) ? whi[1] : whi[3]); \
          _Pragma("unroll")                                                      \
          for (int q = 0; q < 4; ++q) {                                          \
            float pv = (float)pq[q];                                             \
            oacc[rrh*2][q]   += w0v * pv;                                        \
            oacc[rrh*2+1][q] += w1v * pv;                                        \
          }                                                                      \
        }                                                                        \
      }                                                                          \
    }                                                                            \
    BARRIER_LGKM();                                                              \
  } while (0)

  for (int chp = 0; chp < nch; chp += 2) {   // nch is even (36 or 72)
    CHUNK_BODY(chp,     bufA, bufB);
    CHUNK_BODY(chp + 1, bufB, bufA);
  }
#undef CHUNK_BODY

  // ---- epilogue: out[n, oc, X, Yh*32 + wv*8 .. +7] ----
  float* OP = outp + (size_t)g*OUTSZ;
  #pragma unroll
  for (int q = 0; q < 4; ++q) {
    int n = nh*4 + q;
    f32x4 v0, v1;
    v0[0]=oacc[0][q]; v0[1]=oacc[1][q]; v0[2]=oacc[2][q]; v0[3]=oacc[3][q];
    v1[0]=oacc[4][q]; v1[1]=oacc[5][q]; v1[2]=oacc[6][q]; v1[3]=oacc[7][q];
    float* dst = OP + (((size_t)(n*OCC + oc)*XUP + X)*YUP + Yh*32 + wv*8);
    *(f32x4*)dst     = v0;
    *(f32x4*)(dst+4) = v1;
  }
}

// ---------------------------------------------------------------------------
// Kernel 4 (G=2 only): out = P0 + P1 (deterministic)
// ---------------------------------------------------------------------------
__global__ void reduce2(const float* __restrict__ P, float* __restrict__ out) {
  int i = blockIdx.x*256 + threadIdx.x;
  if (i < OUTSZ/4) {
    f32x4 a = ((const f32x4*)P)[i];
    f32x4 b = ((const f32x4*)(P + OUTSZ))[i];
    ((f32x4*)out)[i] = a + b;
  }
}

// ---------------------------------------------------------------------------
extern "C" void kernel_launch(void* const* d_in, const int* in_sizes, int n_in,
                              void* d_out, int out_size, void* d_ws, size_t ws_size,
                              hipStream_t stream) {
  const float* F_LR = (const float*)d_in[0];
  const float* v    = (const float*)d_in[1];
  const float* w1   = (const float*)d_in[2];
  const float* b1   = (const float*)d_in[3];
  const float* w2   = (const float*)d_in[4];
  const float* b2   = (const float*)d_in[5];
  float* out = (float*)d_out;

  const size_t prepBytes = (size_t)RTOT*HID*2;          // 4,718,592 each
  const size_t need2 = 2*prepBytes + 2ull*OUTSZ*4;      // 28,311,552
  const int G   = (ws_size >= need2) ? 2 : 1;
  const int nch = 72 / G;

  __hip_bfloat16* hmidp = (__hip_bfloat16*)d_ws;
  __hip_bfloat16* w2p   = (__hip_bfloat16*)((char*)d_ws + prepBytes);
  float* P = (float*)((char*)d_ws + 2*prepBytes);
  float* target = (G == 2) ? P : out;

  const size_t shmem = 16384 + 27648 + 16384 + (size_t)nch*128*2;   // 65,024 (G=2)

  hipLaunchKernelGGL(prep_hmid, dim3(RTOT), dim3(HID), 0, stream, v, w1, b1, hmidp);
  hipLaunchKernelGGL(prep_w2,   dim3((HID*COLS)/256), dim3(256), 0, stream, w2, w2p);
  hipLaunchKernelGGL(fused_main, dim3(288*G), dim3(256), shmem, stream,
                     F_LR, hmidp, w2p, b2, target, G, nch);
  if (G == 2)
    hipLaunchKernelGGL(reduce2, dim3(OUTSZ/4/256), dim3(256), 0, stream, P, out);
}